// Round 6
// baseline (841.499 us; speedup 1.0000x reference)
//
#include <hip/hip_runtime.h>

// WeightOnlyInt4Linear: out[8192,11008] = x[8192,4096] @ dequant(packed int4 W)
// (1) x -> bf16, (2) W int4 -> bf16 [N][K] transposed, (3) 256x256 bf16 MFMA GEMM
// 8-phase schedule, T2 swizzle, T5 setprio, one vmcnt(6)/K-tile (R5 schedule).
// R6: MFMA shape 16x16x32 -> 32x32x16 (2382 vs 2075 TF ubench, -17% pipe cycles).
// Same LDS layout, same staging/death schedule; only frag maps + epilogue change.

#define M_DIM 8192
#define K_DIM 4096
#define N_DIM 11008
#define BM 256
#define BN 256
#define BK 64
#define NKT (K_DIM / BK)  // 64

typedef unsigned short u16;
typedef __bf16 bf16x8 __attribute__((ext_vector_type(8)));
typedef float floatx16 __attribute__((ext_vector_type(16)));
typedef u16 u16x8 __attribute__((ext_vector_type(8)));
typedef u16 u16x4 __attribute__((ext_vector_type(4)));

typedef __attribute__((address_space(1))) const void* gcvp;
typedef __attribute__((address_space(3))) void* svp;

static __device__ __forceinline__ u16 f2b(float f) {
  union { float f; unsigned u; } v;
  v.f = f;
  unsigned r = v.u + 0x7FFFu + ((v.u >> 16) & 1u);  // RNE, finite inputs
  return (u16)(r >> 16);
}

// ---------------- kernel 1: x f32 -> bf16 ----------------
__global__ __launch_bounds__(256) void cvt_x_kernel(const float* __restrict__ x,
                                                    u16* __restrict__ xb) {
  int i = blockIdx.x * 256 + threadIdx.x;
  const int n4 = (M_DIM * K_DIM) / 4;
  const int stride = 2048 * 256;
  for (; i < n4; i += stride) {
    const float4 v = reinterpret_cast<const float4*>(x)[i];
    u16x4 r;
    r[0] = f2b(v.x); r[1] = f2b(v.y); r[2] = f2b(v.z); r[3] = f2b(v.w);
    reinterpret_cast<u16x4*>(xb)[i] = r;
  }
}

// ---------------- kernel 2: int4 W -> bf16 W^T [N][K] ----------------
__global__ __launch_bounds__(256) void dequant_w_kernel(const int* __restrict__ pw,
                                                        const float* __restrict__ sc,
                                                        const float* __restrict__ zr,
                                                        u16* __restrict__ wbt) {
  __shared__ int tile[64][65];
  const int t = threadIdx.x;
  const int o0 = blockIdx.x * 64;
  const int kw0 = blockIdx.y * 64;
#pragma unroll
  for (int r = 0; r < 16; ++r) {
    const int kw = r * 4 + (t >> 6);
    const int o = t & 63;
    tile[kw][o] = pw[(kw0 + kw) * N_DIM + o0 + o];
  }
  __syncthreads();
  const int kwl = t & 63;
  const int g = (kw0 + kwl) >> 4;
  const int obase = (t >> 6) * 16;
  for (int it = 0; it < 16; ++it) {
    const int ol = obase + it;
    const int o = o0 + ol;
    const float s = sc[o * 32 + g];
    const float z = zr[o * 32 + g];
    const float b = -z * s;
    const int word = tile[kwl][ol];
    u16x8 r;
#pragma unroll
    for (int j = 0; j < 8; ++j) {
      const float q = (float)((word >> (4 * j)) & 0xF);
      r[j] = f2b(fmaf(q, s, b));
    }
    *reinterpret_cast<u16x8*>(&wbt[(size_t)o * K_DIM + (size_t)(kw0 + kwl) * 8]) = r;
  }
}

// ---------------- kernel 3: 256x256 8-phase bf16 MFMA GEMM (32x32x16) ----------------
// 512 thr = 8 waves (2M x 4N); per wave 128x64 out = 4x2 tiles of 32x32.
// LDS: 2 buf x (A[256][64] + B[256][64]) bf16 = 128 KiB, 16B-slot swizzle ^(row&7).

#define WAITL0                                               \
  asm volatile("s_waitcnt lgkmcnt(0)" ::: "memory");         \
  __builtin_amdgcn_sched_barrier(0)
#define WAITV(n)                                             \
  asm volatile("s_waitcnt vmcnt(" #n ")" ::: "memory");      \
  __builtin_amdgcn_sched_barrier(0)
#define BAR __builtin_amdgcn_s_barrier()

__global__ __launch_bounds__(512, 2) void gemm_kernel(const u16* __restrict__ xb,
                                                      const u16* __restrict__ wbt,
                                                      float* __restrict__ out) {
  __shared__ __align__(16) u16 lds[2][2][BM * BK];  // 131072 B

  const int tid = threadIdx.x;
  const int w = tid >> 6;
  const int l = tid & 63;
  const int wm = w >> 2;  // 0..1
  const int wn = w & 3;   // 0..3

  // bijective XCD swizzle: 1376 = 8*172
  const int bid = blockIdx.x;
  const int wg = (bid & 7) * 172 + (bid >> 3);
  const int NT = N_DIM / BN;  // 43
  const int m0 = (wg / NT) * BM;
  const int n0 = (wg % NT) * BN;

  // ---- staging: quarter (64 rows x 64 cols); thread -> row=q*64+(tid>>3), slot=tid&7
  const int sr = tid >> 3;                       // 0..63
  const int scc = ((tid & 7) ^ (sr & 7)) * 8;    // involution slot^(row&7)
  const u16* srcA = xb + (size_t)(m0 + sr) * K_DIM + scc;
  const u16* srcB = wbt + (size_t)(n0 + sr) * K_DIM + scc;

#define STAGEQ(buf, op, q, t)                                                  \
  __builtin_amdgcn_global_load_lds(                                            \
      gcvp(((op) ? srcB : srcA) + (size_t)((q) * 64) * K_DIM + (t) * 64),      \
      svp(&lds[buf][op][((q) * 64 + w * 8) * 64]), 16, 0, 0)

  // ---- 32x32x16 fragment maps ----
  // A: row = wm*128 + mt*32 + (l&31), k = (l>>5)*8 + j  -> 16B slot (ks*2)|(l>>5)
  // swizzled slot = slot ^ (row&7); row&7 == l&7. B mirrors with col-row in B^T.
  int swzk[4];
#pragma unroll
  for (int ks = 0; ks < 4; ++ks) swzk[ks] = ((((ks << 1) | (l >> 5)) ^ (l & 7)) * 8);
  const int baseA = (wm * 128 + (l & 31)) * 64;
  const int baseB = 16384 + (wn * 64 + (l & 31)) * 64;
  const u16* lp = &lds[0][0][0];

  bf16x8 a[2][4], b0[4], b1[4];

#define LDA(cb, S)                                                                      \
  do {                                                                                  \
    _Pragma("unroll") for (int _mt = 0; _mt < 2; ++_mt)                                 \
      _Pragma("unroll") for (int _ks = 0; _ks < 4; ++_ks)                               \
        a[_mt][_ks] = *reinterpret_cast<const bf16x8*>(                                 \
            &lp[(cb) + baseA + ((S) * 2 + _mt) * 2048 + swzk[_ks]]);                    \
  } while (0)
#define LDB(cb, BA, U)                                                                  \
  do {                                                                                  \
    _Pragma("unroll") for (int _ks = 0; _ks < 4; ++_ks)                                 \
      BA[_ks] = *reinterpret_cast<const bf16x8*>(                                       \
          &lp[(cb) + baseB + (U) * 2048 + swzk[_ks]]);                                  \
  } while (0)

  floatx16 acc[4][2] = {};

#define QMFMA(S, BA, U)                                                                 \
  do {                                                                                  \
    __builtin_amdgcn_s_setprio(1);                                                     \
    _Pragma("unroll") for (int _ks = 0; _ks < 4; ++_ks)                                 \
      _Pragma("unroll") for (int _mt = 0; _mt < 2; ++_mt)                               \
        acc[(S) * 2 + _mt][U] = __builtin_amdgcn_mfma_f32_32x32x16_bf16(                \
            a[_mt][_ks], BA[_ks], acc[(S) * 2 + _mt][U], 0, 0, 0);                      \
    __builtin_amdgcn_s_setprio(0);                                                     \
  } while (0)

  // ---- prologue: tile0 fully, tile1 A q0-q3 + B q0,q1 (14 loads)
  STAGEQ(0, 0, 0, 0); STAGEQ(0, 0, 1, 0); STAGEQ(0, 0, 2, 0); STAGEQ(0, 0, 3, 0);
  STAGEQ(0, 1, 0, 0); STAGEQ(0, 1, 1, 0); STAGEQ(0, 1, 2, 0); STAGEQ(0, 1, 3, 0);
  STAGEQ(1, 0, 0, 1); STAGEQ(1, 0, 1, 1); STAGEQ(1, 0, 2, 1); STAGEQ(1, 0, 3, 1);
  STAGEQ(1, 1, 0, 1); STAGEQ(1, 1, 1, 1);
  WAITV(6);
  BAR;

  // ---- main loop: 4 phases / K-tile; ONE vmcnt(6) per tile at p0 (R5 ledger) ----
#pragma unroll 2
  for (int t = 0; t < NKT - 2; ++t) {
    const int buf = t & 1;
    const int sb = buf ^ 1;
    const int cb = buf * 32768;
    // phase 0: read A-sub0 (rows 0-63 of wave) + B U=0; stage B-q2,q3[t+1]
    LDA(cb, 0);
    LDB(cb, b0, 0);
    STAGEQ(sb, 1, 2, t + 1); STAGEQ(sb, 1, 3, t + 1);
    WAITV(6); BAR; WAITL0;
    QMFMA(0, b0, 0);
    BAR;
    // phase 1: read B U=1; stage A-q0,q2[t+2] (A[t] rows 0-63/128-191 dead after p0)
    LDB(cb, b1, 1);
    STAGEQ(buf, 0, 0, t + 2); STAGEQ(buf, 0, 2, t + 2);
    BAR; WAITL0;
    QMFMA(0, b1, 1);
    BAR;
    // phase 2: read A-sub1; stage B-q0,q1[t+2] (B[t] dead after p1)
    LDA(cb, 1);
    STAGEQ(buf, 1, 0, t + 2); STAGEQ(buf, 1, 1, t + 2);
    BAR; WAITL0;
    QMFMA(1, b0, 0);
    BAR;
    // phase 3: stage A-q1,q3[t+2] (A[t] rows 64-127/192-255 dead after p2)
    STAGEQ(buf, 0, 1, t + 2); STAGEQ(buf, 0, 3, t + 2);
    BAR;
    QMFMA(1, b1, 1);
    BAR;
  }

  // ---- peel t = NKT-2 (buf=0): stage only B-q2,q3[NKT-1]; queue ends at 6 ----
  {
    const int cb = 0;
    LDA(cb, 0);
    LDB(cb, b0, 0);
    STAGEQ(1, 1, 2, NKT - 1); STAGEQ(1, 1, 3, NKT - 1);
    WAITV(6); BAR; WAITL0;
    QMFMA(0, b0, 0);
    BAR;
    LDB(cb, b1, 1);
    WAITL0;
    QMFMA(0, b1, 1);
    LDA(cb, 1);
    WAITL0;
    QMFMA(1, b0, 0);
    QMFMA(1, b1, 1);
  }
  // ---- peel t = NKT-1 (buf=1): drain all, publish, barrier-free compute ----
  {
    const int cb = 32768;
    WAITV(0); BAR;
    LDA(cb, 0);
    LDB(cb, b0, 0);
    WAITL0;
    QMFMA(0, b0, 0);
    LDB(cb, b1, 1);
    WAITL0;
    QMFMA(0, b1, 1);
    LDA(cb, 1);
    WAITL0;
    QMFMA(1, b0, 0);
    QMFMA(1, b1, 1);
  }

  // ---- epilogue: 32x32 C/D map col = l&31, row = (reg&3)+8*(reg>>2)+4*(l>>5) ----
  const int ocol0 = n0 + wn * 64 + (l & 31);
  const int orow0 = m0 + wm * 128 + 4 * (l >> 5);
#pragma unroll
  for (int mt = 0; mt < 4; ++mt)
#pragma unroll
    for (int rg = 0; rg < 4; ++rg)
#pragma unroll
      for (int rr = 0; rr < 4; ++rr) {
        const int row = orow0 + mt * 32 + rg * 8 + rr;
        float* op = out + (size_t)row * N_DIM + ocol0;
        op[0] = acc[mt][0][rg * 4 + rr];
        op[32] = acc[mt][1][rg * 4 + rr];
      }
}

// ---------------- fallback: fly-dequant (ws too small) ----------------
__global__ __launch_bounds__(256) void gemm_naive(const float* __restrict__ x,
                                                  const int* __restrict__ pw,
                                                  const float* __restrict__ sc,
                                                  const float* __restrict__ zr,
                                                  float* __restrict__ out) {
  const int idx = blockIdx.x * 256 + threadIdx.x;
  if (idx >= M_DIM * N_DIM) return;
  const int m = idx / N_DIM, o = idx % N_DIM;
  const float* xr = x + (size_t)m * K_DIM;
  float acc = 0.f;
  for (int g = 0; g < 32; ++g) {
    const float s = sc[o * 32 + g];
    const float z = zr[o * 32 + g];
    const float b = -z * s;
    for (int kw = g * 16; kw < g * 16 + 16; ++kw) {
      const int word = pw[kw * N_DIM + o];
#pragma unroll
      for (int j = 0; j < 8; ++j) {
        const float q = (float)((word >> (4 * j)) & 0xF);
        acc += xr[kw * 8 + j] * fmaf(q, s, b);
      }
    }
  }
  out[idx] = acc;
}

extern "C" void kernel_launch(void* const* d_in, const int* in_sizes, int n_in,
                              void* d_out, int out_size, void* d_ws, size_t ws_size,
                              hipStream_t stream) {
  (void)in_sizes; (void)n_in; (void)out_size;
  const float* x = (const float*)d_in[0];
  const int* pw = (const int*)d_in[1];
  const float* sc = (const float*)d_in[2];
  const float* zr = (const float*)d_in[3];
  float* out = (float*)d_out;

  const size_t need = ((size_t)M_DIM * K_DIM + (size_t)N_DIM * K_DIM) * 2;
  if (ws_size >= need) {
    u16* xb = (u16*)d_ws;
    u16* wbt = xb + (size_t)M_DIM * K_DIM;
    cvt_x_kernel<<<2048, 256, 0, stream>>>(x, xb);
    dequant_w_kernel<<<dim3(N_DIM / 64, (K_DIM / 8) / 64), 256, 0, stream>>>(pw, sc, zr, wbt);
    gemm_kernel<<<(M_DIM / BM) * (N_DIM / BN), 512, 0, stream>>>(xb, wbt, out);
  } else {
    gemm_naive<<<(M_DIM * N_DIM + 255) / 256, 256, 0, stream>>>(x, pw, sc, zr, out);
  }
}

// Round 7
// 718.281 us; speedup vs baseline: 1.1715x; 1.1715x over previous
//
#include <hip/hip_runtime.h>

// WeightOnlyInt4Linear: out[8192,11008] = x[8192,4096] @ dequant(packed int4 W)
// (1) x -> bf16, (2) W int4 -> bf16 [N][K] transposed, (3) 256x256 bf16 MFMA GEMM
// 8-phase schedule, T2 swizzle (16x16 pattern, measured 0 conflicts), T5 setprio,
// per-phase WAITV(6) (R4 ledger-safe scheme). R7: barrier moved PRE-MFMA
// ({...WAITV,BAR,WAITL0,BAR,MFMA}) to de-lockstep waves; p3 has a single BAR.

#define M_DIM 8192
#define K_DIM 4096
#define N_DIM 11008
#define BM 256
#define BN 256
#define BK 64
#define NKT (K_DIM / BK)  // 64

typedef unsigned short u16;
typedef __bf16 bf16x8 __attribute__((ext_vector_type(8)));
typedef float floatx4 __attribute__((ext_vector_type(4)));
typedef u16 u16x8 __attribute__((ext_vector_type(8)));
typedef u16 u16x4 __attribute__((ext_vector_type(4)));

typedef __attribute__((address_space(1))) const void* gcvp;
typedef __attribute__((address_space(3))) void* svp;

static __device__ __forceinline__ u16 f2b(float f) {
  union { float f; unsigned u; } v;
  v.f = f;
  unsigned r = v.u + 0x7FFFu + ((v.u >> 16) & 1u);  // RNE, finite inputs
  return (u16)(r >> 16);
}

// ---------------- kernel 1: x f32 -> bf16 ----------------
__global__ __launch_bounds__(256) void cvt_x_kernel(const float* __restrict__ x,
                                                    u16* __restrict__ xb) {
  int i = blockIdx.x * 256 + threadIdx.x;
  const int n4 = (M_DIM * K_DIM) / 4;
  const int stride = 2048 * 256;
  for (; i < n4; i += stride) {
    const float4 v = reinterpret_cast<const float4*>(x)[i];
    u16x4 r;
    r[0] = f2b(v.x); r[1] = f2b(v.y); r[2] = f2b(v.z); r[3] = f2b(v.w);
    reinterpret_cast<u16x4*>(xb)[i] = r;
  }
}

// ---------------- kernel 2: int4 W -> bf16 W^T [N][K] ----------------
__global__ __launch_bounds__(256) void dequant_w_kernel(const int* __restrict__ pw,
                                                        const float* __restrict__ sc,
                                                        const float* __restrict__ zr,
                                                        u16* __restrict__ wbt) {
  __shared__ int tile[64][65];
  const int t = threadIdx.x;
  const int o0 = blockIdx.x * 64;
  const int kw0 = blockIdx.y * 64;
#pragma unroll
  for (int r = 0; r < 16; ++r) {
    const int kw = r * 4 + (t >> 6);
    const int o = t & 63;
    tile[kw][o] = pw[(kw0 + kw) * N_DIM + o0 + o];
  }
  __syncthreads();
  const int kwl = t & 63;
  const int g = (kw0 + kwl) >> 4;
  const int obase = (t >> 6) * 16;
  for (int it = 0; it < 16; ++it) {
    const int ol = obase + it;
    const int o = o0 + ol;
    const float s = sc[o * 32 + g];
    const float z = zr[o * 32 + g];
    const float b = -z * s;
    const int word = tile[kwl][ol];
    u16x8 r;
#pragma unroll
    for (int j = 0; j < 8; ++j) {
      const float q = (float)((word >> (4 * j)) & 0xF);
      r[j] = f2b(fmaf(q, s, b));
    }
    *reinterpret_cast<u16x8*>(&wbt[(size_t)o * K_DIM + (size_t)(kw0 + kwl) * 8]) = r;
  }
}

// ---------------- kernel 3: 256x256 8-phase bf16 MFMA GEMM (16x16x32) ----------------
// 512 thr = 8 waves (2M x 4N); per wave 128x64 out = 8x4 frags of 16x16x32.
// LDS: 2 buf x (A[256][64] + B[256][64]) bf16 = 128 KiB, 16B-slot swizzle ^(row&7).

#define WAITL0                                               \
  asm volatile("s_waitcnt lgkmcnt(0)" ::: "memory");         \
  __builtin_amdgcn_sched_barrier(0)
#define WAITV(n)                                             \
  asm volatile("s_waitcnt vmcnt(" #n ")" ::: "memory");      \
  __builtin_amdgcn_sched_barrier(0)
#define BAR __builtin_amdgcn_s_barrier()

__global__ __launch_bounds__(512, 2) void gemm_kernel(const u16* __restrict__ xb,
                                                      const u16* __restrict__ wbt,
                                                      float* __restrict__ out) {
  __shared__ __align__(16) u16 lds[2][2][BM * BK];  // 131072 B

  const int tid = threadIdx.x;
  const int w = tid >> 6;
  const int l = tid & 63;
  const int wm = w >> 2;  // 0..1
  const int wn = w & 3;   // 0..3

  // bijective XCD swizzle: 1376 = 8*172
  const int bid = blockIdx.x;
  const int wg = (bid & 7) * 172 + (bid >> 3);
  const int NT = N_DIM / BN;  // 43
  const int m0 = (wg / NT) * BM;
  const int n0 = (wg % NT) * BN;

  // ---- staging: quarter (64 rows x 64 cols); thread -> row=q*64+(tid>>3), slot=tid&7
  const int sr = tid >> 3;                       // 0..63
  const int scc = ((tid & 7) ^ (sr & 7)) * 8;    // involution slot^(row&7)
  const u16* srcA = xb + (size_t)(m0 + sr) * K_DIM + scc;
  const u16* srcB = wbt + (size_t)(n0 + sr) * K_DIM + scc;

#define STAGEQ(buf, op, q, t)                                                  \
  __builtin_amdgcn_global_load_lds(                                            \
      gcvp(((op) ? srcB : srcA) + (size_t)((q) * 64) * K_DIM + (t) * 64),      \
      svp(&lds[buf][op][((q) * 64 + w * 8) * 64]), 16, 0, 0)

  // ---- fragment bases (elem offsets, swizzled read side); kk=1 addr = kk=0 ^ 32
  const int swz = ((l >> 4) ^ (l & 7)) * 8;
  const int baseA = (wm * 128 + (l & 15)) * 64 + swz;
  const int baseB = 16384 + (wn * 64 + (l & 15)) * 64 + swz;
  const u16* lp = &lds[0][0][0];

  bf16x8 a[4][2], b0[2][2], b1[2][2];

#define LDA(cb, S)                                                                      \
  do {                                                                                  \
    _Pragma("unroll") for (int _m = 0; _m < 4; ++_m) {                                  \
      const int _e = (cb) + baseA + ((S) * 4 + _m) * 1024;                              \
      a[_m][0] = *reinterpret_cast<const bf16x8*>(&lp[_e]);                             \
      a[_m][1] = *reinterpret_cast<const bf16x8*>(&lp[_e ^ 32]);                        \
    }                                                                                   \
  } while (0)
#define LDB(cb, BA, U)                                                                  \
  do {                                                                                  \
    _Pragma("unroll") for (int _n = 0; _n < 2; ++_n) {                                  \
      const int _e = (cb) + baseB + ((U) * 2 + _n) * 1024;                              \
      BA[_n][0] = *reinterpret_cast<const bf16x8*>(&lp[_e]);                            \
      BA[_n][1] = *reinterpret_cast<const bf16x8*>(&lp[_e ^ 32]);                       \
    }                                                                                   \
  } while (0)

  floatx4 acc[8][4] = {};

#define QMFMA(S, BA, U)                                                                 \
  do {                                                                                  \
    __builtin_amdgcn_s_setprio(1);                                                     \
    _Pragma("unroll") for (int _m = 0; _m < 4; ++_m)                                    \
      _Pragma("unroll") for (int _n = 0; _n < 2; ++_n)                                  \
        _Pragma("unroll") for (int _k = 0; _k < 2; ++_k)                                \
          acc[(S) * 4 + _m][(U) * 2 + _n] = __builtin_amdgcn_mfma_f32_16x16x32_bf16(    \
              a[_m][_k], BA[_n][_k], acc[(S) * 4 + _m][(U) * 2 + _n], 0, 0, 0);         \
    __builtin_amdgcn_s_setprio(0);                                                     \
  } while (0)

  // ---- prologue: tile0 fully, tile1 A q0-q3 + B q0,q1 (14 loads)
  STAGEQ(0, 0, 0, 0); STAGEQ(0, 0, 1, 0); STAGEQ(0, 0, 2, 0); STAGEQ(0, 0, 3, 0);
  STAGEQ(0, 1, 0, 0); STAGEQ(0, 1, 1, 0); STAGEQ(0, 1, 2, 0); STAGEQ(0, 1, 3, 0);
  STAGEQ(1, 0, 0, 1); STAGEQ(1, 0, 1, 1); STAGEQ(1, 0, 2, 1); STAGEQ(1, 0, 3, 1);
  STAGEQ(1, 1, 0, 1); STAGEQ(1, 1, 1, 1);
  WAITV(6);
  BAR;

  // ---- main loop: 4 phases / K-tile; per-phase WAITV(6); BAR pre-MFMA ----
  // Ledger: (t-1)p3's WAITV(6) retires through B2B3[t] => tile t confirmed before
  // its p0 reads. Each stage follows the BAR after its region's last-read WAITL0.
#pragma unroll 2
  for (int t = 0; t < NKT - 2; ++t) {
    const int buf = t & 1;
    const int sb = buf ^ 1;
    const int cb = buf * 32768;
    // phase 0: read A-sub0 + B-sub0 of tile t; stage B-q2,q3[t+1]
    LDA(cb, 0);
    LDB(cb, b0, 0);
    STAGEQ(sb, 1, 2, t + 1); STAGEQ(sb, 1, 3, t + 1);
    WAITV(6); BAR; WAITL0; BAR;
    QMFMA(0, b0, 0);
    // phase 1: read B-sub1; stage A-q0,q2[t+2] (A[t] q0,q2 last read p0)
    LDB(cb, b1, 1);
    STAGEQ(buf, 0, 0, t + 2); STAGEQ(buf, 0, 2, t + 2);
    WAITV(6); BAR; WAITL0; BAR;
    QMFMA(0, b1, 1);
    // phase 2: read A-sub1; stage B-q0,q1[t+2] (B[t] last read p1)
    LDA(cb, 1);
    STAGEQ(buf, 1, 0, t + 2); STAGEQ(buf, 1, 1, t + 2);
    WAITV(6); BAR; WAITL0; BAR;
    QMFMA(1, b0, 0);
    // phase 3: stage A-q1,q3[t+2] (A[t] q1,q3 last read p2); no reads -> one BAR
    STAGEQ(buf, 0, 1, t + 2); STAGEQ(buf, 0, 3, t + 2);
    WAITV(6); BAR;
    QMFMA(1, b1, 1);
  }

  // ---- peel t = NKT-2 (buf=0): progressive drain 6->4->2->0 of tile NKT-1 ----
  {
    const int cb = 0;
    LDA(cb, 0);
    LDB(cb, b0, 0);
    STAGEQ(1, 1, 2, NKT - 1); STAGEQ(1, 1, 3, NKT - 1);
    WAITV(6); BAR; WAITL0; BAR;   // retires A0,A2[NKT-1]
    QMFMA(0, b0, 0);
    LDB(cb, b1, 1);
    WAITV(4); BAR; WAITL0; BAR;   // retires B0,B1[NKT-1]
    QMFMA(0, b1, 1);
    LDA(cb, 1);
    WAITV(2); BAR; WAITL0; BAR;   // retires A1,A3[NKT-1]
    QMFMA(1, b0, 0);
    WAITV(0); BAR;                // retires B2,B3[NKT-1]; publishes to all waves
    QMFMA(1, b1, 1);
  }
  // ---- peel t = NKT-1 (buf=1): all landed & published; barrier-free ----
  {
    const int cb = 32768;
    LDA(cb, 0);
    LDB(cb, b0, 0);
    WAITL0;
    QMFMA(0, b0, 0);
    LDB(cb, b1, 1);
    WAITL0;
    QMFMA(0, b1, 1);
    LDA(cb, 1);
    WAITL0;
    QMFMA(1, b0, 0);
    QMFMA(1, b1, 1);
  }

  // ---- epilogue: C/D map col = l&15, row = (l>>4)*4 + j (verified R1/R2) ----
  const int orow0 = m0 + wm * 128 + (l >> 4) * 4;
  const int ocol0 = n0 + wn * 64 + (l & 15);
#pragma unroll
  for (int mi = 0; mi < 8; ++mi)
#pragma unroll
    for (int j = 0; j < 4; ++j) {
      float* op = out + (size_t)(orow0 + mi * 16 + j) * N_DIM + ocol0;
#pragma unroll
      for (int ni = 0; ni < 4; ++ni) op[ni * 16] = acc[mi][ni][j];
    }
}

// ---------------- fallback: fly-dequant (ws too small) ----------------
__global__ __launch_bounds__(256) void gemm_naive(const float* __restrict__ x,
                                                  const int* __restrict__ pw,
                                                  const float* __restrict__ sc,
                                                  const float* __restrict__ zr,
                                                  float* __restrict__ out) {
  const int idx = blockIdx.x * 256 + threadIdx.x;
  if (idx >= M_DIM * N_DIM) return;
  const int m = idx / N_DIM, o = idx % N_DIM;
  const float* xr = x + (size_t)m * K_DIM;
  float acc = 0.f;
  for (int g = 0; g < 32; ++g) {
    const float s = sc[o * 32 + g];
    const float z = zr[o * 32 + g];
    const float b = -z * s;
    for (int kw = g * 16; kw < g * 16 + 16; ++kw) {
      const int word = pw[kw * N_DIM + o];
#pragma unroll
      for (int j = 0; j < 8; ++j) {
        const float q = (float)((word >> (4 * j)) & 0xF);
        acc += xr[kw * 8 + j] * fmaf(q, s, b);
      }
    }
  }
  out[idx] = acc;
}

extern "C" void kernel_launch(void* const* d_in, const int* in_sizes, int n_in,
                              void* d_out, int out_size, void* d_ws, size_t ws_size,
                              hipStream_t stream) {
  (void)in_sizes; (void)n_in; (void)out_size;
  const float* x = (const float*)d_in[0];
  const int* pw = (const int*)d_in[1];
  const float* sc = (const float*)d_in[2];
  const float* zr = (const float*)d_in[3];
  float* out = (float*)d_out;

  const size_t need = ((size_t)M_DIM * K_DIM + (size_t)N_DIM * K_DIM) * 2;
  if (ws_size >= need) {
    u16* xb = (u16*)d_ws;
    u16* wbt = xb + (size_t)M_DIM * K_DIM;
    cvt_x_kernel<<<2048, 256, 0, stream>>>(x, xb);
    dequant_w_kernel<<<dim3(N_DIM / 64, (K_DIM / 8) / 64), 256, 0, stream>>>(pw, sc, zr, wbt);
    gemm_kernel<<<(M_DIM / BM) * (N_DIM / BN), 512, 0, stream>>>(xb, wbt, out);
  } else {
    gemm_naive<<<(M_DIM * N_DIM + 255) / 256, 256, 0, stream>>>(x, pw, sc, zr, out);
  }
}